// Round 1
// 320.007 us; speedup vs baseline: 1.0227x; 1.0227x over previous
//
#include <hip/hip_runtime.h>

#define H 2048
#define NH 16
#define NKV 4
#define HD 128
#define CTX 8192
#define IDIM 8192
#define EPS 1e-6f
#define SCALE 0.08838834764831845f

__device__ __forceinline__ float wave_sum(float x){
#pragma unroll
    for(int o=32;o>0;o>>=1) x += __shfl_xor(x,o,64);
    return x;
}
__device__ __forceinline__ float wave_max(float x){
#pragma unroll
    for(int o=32;o>0;o>>=1) x = fmaxf(x,__shfl_xor(x,o,64));
    return x;
}

// ---------- K1: fused ln1-RMSNorm + QKV matvec. grid 1280 x 256 ----------
// Weight loads issued FIRST, pinned with sched_barrier(0) so all 8 float4
// stay in flight while the block computes the redundant RMS norm (latency
// of the weight stream hides under the norm phase).
__global__ __launch_bounds__(256) void k_qkv(const float* __restrict__ Wq,
                                             const float* __restrict__ Wk,
                                             const float* __restrict__ Wv,
                                             const float* __restrict__ hs,
                                             const float* __restrict__ ln1,
                                             float* __restrict__ qg,
                                             float* __restrict__ kvec,
                                             float* __restrict__ vvec){
    __shared__ __align__(16) float hw[H];
    __shared__ float red[4];
    int tid = threadIdx.x, wid = tid>>6, lane = tid&63;
    int row = blockIdx.x*4 + wid;
    const float* wr; float* op;
    if(row < 4096)      { wr = Wq + (size_t)row*H;        op = qg   + row; }
    else if(row < 4608) { wr = Wk + (size_t)(row-4096)*H; op = kvec + (row-4096); }
    else                { wr = Wv + (size_t)(row-4608)*H; op = vvec + (row-4608); }
    // small vector loads first (so waiting on them doesn't drain the weight queue)
    float4 a = *(const float4*)(hs + tid*8);
    float4 b = *(const float4*)(hs + tid*8 + 4);
    float4 wa = *(const float4*)(ln1 + tid*8);
    float4 wb = *(const float4*)(ln1 + tid*8 + 4);
    // stage the full 8KB weight row across the wave: 8 float4/lane in flight
    float4 r[8];
#pragma unroll
    for(int i=0;i<8;i++) r[i] = *(const float4*)(wr + i*256 + lane*4);
    __builtin_amdgcn_sched_barrier(0);   // loads may NOT sink past this point

    float ss = a.x*a.x+a.y*a.y+a.z*a.z+a.w*a.w + b.x*b.x+b.y*b.y+b.z*b.z+b.w*b.w;
    ss = wave_sum(ss);
    if(lane==0) red[wid] = ss;
    __syncthreads();
    float rs = rsqrtf((red[0]+red[1]+red[2]+red[3])/(float)H + EPS);
    hw[tid*8+0]=a.x*rs*wa.x; hw[tid*8+1]=a.y*rs*wa.y;
    hw[tid*8+2]=a.z*rs*wa.z; hw[tid*8+3]=a.w*rs*wa.w;
    hw[tid*8+4]=b.x*rs*wb.x; hw[tid*8+5]=b.y*rs*wb.y;
    hw[tid*8+6]=b.z*rs*wb.z; hw[tid*8+7]=b.w*rs*wb.w;
    __syncthreads();

    float acc = 0.f;
#pragma unroll
    for(int i=0;i<8;i++){
        const float* hp = hw + i*256 + lane*4;
        acc += r[i].x*hp[0] + r[i].y*hp[1] + r[i].z*hp[2] + r[i].w*hp[3];
    }
    acc = wave_sum(acc);
    if(lane==0) *op = acc;
}

// ---------- K2: q/k RMS + RoPE + gate sigmoid. grid 20 x 64 ----------
__global__ __launch_bounds__(64) void k_rope(const float* __restrict__ qg,
                                             const float* __restrict__ kvec,
                                             const float* __restrict__ vvec,
                                             const int* __restrict__ pos,
                                             const float* __restrict__ qn,
                                             const float* __restrict__ kn,
                                             const float* __restrict__ rc,
                                             const float* __restrict__ rsn,
                                             float* __restrict__ q_rope,
                                             float* __restrict__ gate_sig,
                                             float* __restrict__ knew,
                                             float* __restrict__ vnew){
    int b = blockIdx.x, lane = threadIdx.x;
    int p = pos[0];
    float c = rc[(size_t)p*64 + lane];
    float s = rsn[(size_t)p*64 + lane];
    if(b < NH){
        int h = b;
        float x1 = qg[h*256 + lane], x2 = qg[h*256 + 64 + lane];
        float ssq = wave_sum(x1*x1 + x2*x2);
        float r = rsqrtf(ssq/128.f + EPS);
        float n1 = x1*r*qn[lane];
        float n2 = x2*r*qn[lane+64];
        q_rope[h*128 + lane]      = n1*c - n2*s;
        q_rope[h*128 + 64 + lane] = n2*c + n1*s;
        float g1 = qg[h*256 + 128 + lane], g2 = qg[h*256 + 192 + lane];
        gate_sig[h*128 + lane]      = 1.f/(1.f + __expf(-g1));
        gate_sig[h*128 + 64 + lane] = 1.f/(1.f + __expf(-g2));
    } else {
        int j = b - NH;
        float x1 = kvec[j*128 + lane], x2 = kvec[j*128 + 64 + lane];
        float ssq = wave_sum(x1*x1 + x2*x2);
        float r = rsqrtf(ssq/128.f + EPS);
        float n1 = x1*r*kn[lane];
        float n2 = x2*r*kn[lane+64];
        knew[j*128 + lane]      = n1*c - n2*s;
        knew[j*128 + 64 + lane] = n2*c + n1*s;
        vnew[j*128 + lane]      = vvec[j*128 + lane];
        vnew[j*128 + 64 + lane] = vvec[j*128 + 64 + lane];
    }
}

// ---------- K3: flash-decode partials. grid (nchunk, NKV) x 128 ----------
// K-dot staged 8 x float4 per group; V-accumulate staged 16 rows per group.
// Each group's loads are fenced so they all stay in flight; the scheduler
// may still overlap group g's FMAs with group g+1's loads (loads sit between
// barriers g and g+1).
__global__ __launch_bounds__(128) void k_attn_part(const float* __restrict__ cache,
                                                   const float* __restrict__ q_rope,
                                                   const float* __restrict__ mask,
                                                   const int* __restrict__ pos,
                                                   const float* __restrict__ knew,
                                                   const float* __restrict__ vnew,
                                                   float* __restrict__ part_m,
                                                   float* __restrict__ part_l,
                                                   float* __restrict__ part_o,
                                                   int nchunk, int chunk){
    int j = blockIdx.y, ci = blockIdx.x, tid = threadIdx.x;
    int p = pos[0];
    __shared__ float q_s[512];
    __shared__ float s_s[512];
    __shared__ float m_s[4], l_s[4], mt_s[4], lt_s[4];
#pragma unroll
    for(int t=0;t<4;t++) q_s[t*128 + tid] = q_rope[j*512 + t*128 + tid];
    if(tid < 4){ m_s[tid] = -3.0e38f; l_s[tid] = 0.f; }
    float o0=0.f,o1=0.f,o2=0.f,o3=0.f;
    __syncthreads();
    int base0 = ci*chunk;
    for(int s0=0; s0<chunk; s0+=128){
        int c = base0 + s0 + tid;
        const float* kr = (c==p) ? (knew + (size_t)j*HD)
                                 : (cache + ((size_t)j*CTX + c)*HD);
        float a0=0.f,a1=0.f,a2=0.f,a3=0.f;
        for(int d0=0; d0<HD; d0+=32){
            float4 u8[8];
#pragma unroll
            for(int t=0;t<8;t++) u8[t] = *(const float4*)(kr + d0 + t*4);
            __builtin_amdgcn_sched_barrier(0);
#pragma unroll
            for(int t=0;t<8;t++){
                int dd = d0 + t*4;
                const float* q0=q_s+dd; const float* q1=q_s+128+dd;
                const float* q2=q_s+256+dd; const float* q3=q_s+384+dd;
                a0 += q0[0]*u8[t].x+q0[1]*u8[t].y+q0[2]*u8[t].z+q0[3]*u8[t].w;
                a1 += q1[0]*u8[t].x+q1[1]*u8[t].y+q1[2]*u8[t].z+q1[3]*u8[t].w;
                a2 += q2[0]*u8[t].x+q2[1]*u8[t].y+q2[2]*u8[t].z+q2[3]*u8[t].w;
                a3 += q3[0]*u8[t].x+q3[1]*u8[t].y+q3[2]*u8[t].z+q3[3]*u8[t].w;
            }
        }
        float mv = mask[c];
        s_s[tid]       = a0*SCALE + mv;
        s_s[128 + tid] = a1*SCALE + mv;
        s_s[256 + tid] = a2*SCALE + mv;
        s_s[384 + tid] = a3*SCALE + mv;
        __syncthreads();
        int wid = tid>>6, lane = tid&63;
#pragma unroll
        for(int hh=0; hh<2; hh++){
            int h = wid*2 + hh;
            float v0 = s_s[h*128 + lane], v1 = s_s[h*128 + 64 + lane];
            float m = wave_max(fmaxf(v0, v1));
            float l = wave_sum(__expf(v0 - m) + __expf(v1 - m));
            if(lane==0){ mt_s[h]=m; lt_s[h]=l; }
        }
        __syncthreads();
        float mn[4], sc_old[4];
#pragma unroll
        for(int h=0;h<4;h++){
            mn[h] = fmaxf(m_s[h], mt_s[h]);
            sc_old[h] = __expf(m_s[h] - mn[h]);
        }
        float w0 = __expf(s_s[tid]       - mn[0]);
        float w1 = __expf(s_s[128 + tid] - mn[1]);
        float w2 = __expf(s_s[256 + tid] - mn[2]);
        float w3 = __expf(s_s[384 + tid] - mn[3]);
        __syncthreads();
        s_s[tid]=w0; s_s[128+tid]=w1; s_s[256+tid]=w2; s_s[384+tid]=w3;
        if(tid < 4){
            l_s[tid] = l_s[tid]*sc_old[tid] + lt_s[tid]*__expf(mt_s[tid] - mn[tid]);
            m_s[tid] = mn[tid];
        }
        __syncthreads();
        o0 *= sc_old[0]; o1 *= sc_old[1]; o2 *= sc_old[2]; o3 *= sc_old[3];
        const float* vb = cache + (size_t)NKV*CTX*HD + ((size_t)j*CTX + base0 + s0)*HD;
        for(int cc0=0; cc0<128; cc0+=16){
            float v[16];
#pragma unroll
            for(int t=0;t<16;t++){
                int gpos = base0 + s0 + cc0 + t;   // wave-uniform select
                const float* vrow = (gpos==p) ? (vnew + (size_t)j*HD)
                                              : (vb + (size_t)(cc0+t)*HD);
                v[t] = vrow[tid];
            }
            __builtin_amdgcn_sched_barrier(0);
#pragma unroll
            for(int t=0;t<16;t++){
                int cc = cc0 + t;
                o0 += s_s[cc]*v[t];
                o1 += s_s[128+cc]*v[t];
                o2 += s_s[256+cc]*v[t];
                o3 += s_s[384+cc]*v[t];
            }
        }
        __syncthreads();
    }
    int h0 = j*4;
    part_o[((size_t)(h0+0)*nchunk + ci)*128 + tid] = o0;
    part_o[((size_t)(h0+1)*nchunk + ci)*128 + tid] = o1;
    part_o[((size_t)(h0+2)*nchunk + ci)*128 + tid] = o2;
    part_o[((size_t)(h0+3)*nchunk + ci)*128 + tid] = o3;
    if(tid < 4){
        part_m[(h0+tid)*nchunk + ci] = m_s[tid];
        part_l[(h0+tid)*nchunk + ci] = l_s[tid];
    }
}

// ---------- K4: combine chunks + gate. grid 16 x 128 ----------
__global__ __launch_bounds__(128) void k_attn_red(const float* __restrict__ part_m,
                                                  const float* __restrict__ part_l,
                                                  const float* __restrict__ part_o,
                                                  const float* __restrict__ gate_sig,
                                                  float* __restrict__ attn,
                                                  int nchunk){
    int h = blockIdx.x, d = threadIdx.x;
    float mg = -3.0e38f;
    for(int i=0;i<nchunk;i++) mg = fmaxf(mg, part_m[h*nchunk + i]);
    float lg = 0.f, oa = 0.f;
    for(int i=0;i<nchunk;i++){
        float e = __expf(part_m[h*nchunk + i] - mg);
        lg += part_l[h*nchunk + i]*e;
        oa += e*part_o[((size_t)h*nchunk + i)*128 + d];
    }
    attn[h*128 + d] = oa/lg * gate_sig[h*128 + d];
}

// ---------- K5: Wo matvec + residual, staged + fenced. grid 512 x 256 ----------
__global__ __launch_bounds__(256) void k_wo(const float* __restrict__ Wo,
                                            const float* __restrict__ attn,
                                            const float* __restrict__ resid,
                                            float* __restrict__ x){
    int wid = threadIdx.x>>6, lane = threadIdx.x&63;
    int row = blockIdx.x*4 + wid;
    const float* wr = Wo + (size_t)row*H;
    float4 r[8];
#pragma unroll
    for(int i=0;i<8;i++) r[i] = *(const float4*)(wr + i*256 + lane*4);
    __builtin_amdgcn_sched_barrier(0);
    float acc = 0.f;
#pragma unroll
    for(int i=0;i<8;i++){
        float4 hv = *(const float4*)(attn + i*256 + lane*4);
        acc += r[i].x*hv.x + r[i].y*hv.y + r[i].z*hv.z + r[i].w*hv.w;
    }
    acc = wave_sum(acc);
    if(lane==0) x[row] = resid[row] + acc;
}

// ---------- K6: fused ln2-RMSNorm + gate/up matvec + SiLU. grid 2048 x 256 ----------
// k_rms folded in: each block redundantly normalizes xres (bit-identical
// arithmetic to the old k_rms), overlapping the 16-deep weight stage.
__global__ __launch_bounds__(256) void k_gateup(const float* __restrict__ Wg,
                                                const float* __restrict__ Wu,
                                                const float* __restrict__ xres,
                                                const float* __restrict__ ln2,
                                                float* __restrict__ act){
    __shared__ __align__(16) float hw[H];
    __shared__ float red[4];
    int tid = threadIdx.x, wid = tid>>6, lane = tid&63;
    int row = blockIdx.x*4 + wid;
    const float* gr = Wg + (size_t)row*H;
    const float* ur = Wu + (size_t)row*H;
    // small vector loads first
    float4 a = *(const float4*)(xres + (size_t)tid*8);
    float4 b = *(const float4*)(xres + (size_t)tid*8 + 4);
    float4 wa = *(const float4*)(ln2 + (size_t)tid*8);
    float4 wb = *(const float4*)(ln2 + (size_t)tid*8 + 4);
    // stage both weight rows: 16 float4/lane in flight
    float4 g[8], u[8];
#pragma unroll
    for(int i=0;i<8;i++) g[i] = *(const float4*)(gr + i*256 + lane*4);
#pragma unroll
    for(int i=0;i<8;i++) u[i] = *(const float4*)(ur + i*256 + lane*4);
    __builtin_amdgcn_sched_barrier(0);

    float x[8] = {a.x,a.y,a.z,a.w,b.x,b.y,b.z,b.w};
    float ss = 0.f;
#pragma unroll
    for(int i=0;i<8;i++) ss += x[i]*x[i];
    ss = wave_sum(ss);
    if(lane==0) red[wid] = ss;
    __syncthreads();
    float tot = red[0]+red[1]+red[2]+red[3];
    float rs = rsqrtf(tot/(float)H + EPS);
    hw[tid*8+0]=x[0]*rs*wa.x; hw[tid*8+1]=x[1]*rs*wa.y;
    hw[tid*8+2]=x[2]*rs*wa.z; hw[tid*8+3]=x[3]*rs*wa.w;
    hw[tid*8+4]=x[4]*rs*wb.x; hw[tid*8+5]=x[5]*rs*wb.y;
    hw[tid*8+6]=x[6]*rs*wb.z; hw[tid*8+7]=x[7]*rs*wb.w;
    __syncthreads();

    float ag = 0.f, au = 0.f;
#pragma unroll
    for(int i=0;i<8;i++){
        const float* hp = hw + i*256 + lane*4;
        ag += g[i].x*hp[0] + g[i].y*hp[1] + g[i].z*hp[2] + g[i].w*hp[3];
        au += u[i].x*hp[0] + u[i].y*hp[1] + u[i].z*hp[2] + u[i].w*hp[3];
    }
    ag = wave_sum(ag);
    au = wave_sum(au);
    if(lane==0){
        float sg = ag/(1.f + __expf(-ag));
        act[row] = sg*au;
    }
}

// ---------- K7: down matvec + residual, staged + fenced. grid 1024 x 256 ----------
__global__ __launch_bounds__(256) void k_down(const float* __restrict__ Wd,
                                              const float* __restrict__ act,
                                              const float* __restrict__ x,
                                              float* __restrict__ out){
    __shared__ float part[4];
    int tid = threadIdx.x, wid = tid>>6, lane = tid&63;
    int row  = blockIdx.x*2 + (wid>>1);
    int half = wid&1;
    const float* wr = Wd + (size_t)row*IDIM + half*4096;
    float4 r[16];
#pragma unroll
    for(int i=0;i<16;i++) r[i] = *(const float4*)(wr + i*256 + lane*4);
    __builtin_amdgcn_sched_barrier(0);
    float acc = 0.f;
#pragma unroll
    for(int i=0;i<16;i++){
        float4 av = *(const float4*)(act + half*4096 + i*256 + lane*4);
        acc += r[i].x*av.x + r[i].y*av.y + r[i].z*av.z + r[i].w*av.w;
    }
    acc = wave_sum(acc);
    if(lane==0) part[wid] = acc;
    __syncthreads();
    if(tid < 2){
        int rr = blockIdx.x*2 + tid;
        out[rr] = x[rr] + part[tid*2] + part[tid*2+1];
    }
}

extern "C" void kernel_launch(void* const* d_in, const int* in_sizes, int n_in,
                              void* d_out, int out_size, void* d_ws, size_t ws_size,
                              hipStream_t stream){
    const float* hs   = (const float*)d_in[0];
    const int*   pos  = (const int*)d_in[1];
    const float* mask = (const float*)d_in[2];
    const float* Wq   = (const float*)d_in[3];
    const float* Wk   = (const float*)d_in[4];
    const float* Wv   = (const float*)d_in[5];
    const float* Wo   = (const float*)d_in[6];
    const float* qn   = (const float*)d_in[7];
    const float* kn   = (const float*)d_in[8];
    const float* ln1  = (const float*)d_in[9];
    const float* ln2  = (const float*)d_in[10];
    const float* Wg   = (const float*)d_in[11];
    const float* Wu   = (const float*)d_in[12];
    const float* Wd   = (const float*)d_in[13];
    const float* cache= (const float*)d_in[14];
    const float* rc   = (const float*)d_in[15];
    const float* rsn  = (const float*)d_in[16];
    float* out = (float*)d_out;

    float* ws       = (float*)d_ws;
    float* qg       = ws;                // 4096
    float* kvec     = ws + 4096;         // 512
    float* vvec     = ws + 4608;         // 512
    float* q_rope   = ws + 5120;         // 2048
    float* gate_sig = ws + 7168;         // 2048
    float* xres     = ws + 9216;         // 2048
    float* attn     = ws + 15360;        // 2048
    float* act      = ws + 17408;        // 8192
    float* knew     = ws + 25600;        // 512
    float* vnew     = ws + 26112;        // 512
    int nchunk = 64;
    while(nchunk > 1){
        size_t need = (size_t)(26624 + 2*NH*nchunk + (size_t)NH*nchunk*128) * 4;
        if(need <= ws_size) break;
        nchunk >>= 1;
    }
    int chunk = CTX / nchunk;
    float* part_m = ws + 26624;
    float* part_l = part_m + NH*nchunk;
    float* part_o = part_l + NH*nchunk;

    k_qkv<<<1280,256,0,stream>>>(Wq, Wk, Wv, hs, ln1, qg, kvec, vvec);
    k_rope<<<20,64,0,stream>>>(qg, kvec, vvec, pos, qn, kn, rc, rsn, q_rope, gate_sig, knew, vnew);
    dim3 g3(nchunk, NKV);
    k_attn_part<<<g3,128,0,stream>>>(cache, q_rope, mask, pos, knew, vnew,
                                     part_m, part_l, part_o, nchunk, chunk);
    k_attn_red<<<16,128,0,stream>>>(part_m, part_l, part_o, gate_sig, attn, nchunk);
    k_wo<<<512,256,0,stream>>>(Wo, attn, hs, xres);
    k_gateup<<<2048,256,0,stream>>>(Wg, Wu, xres, ln2, act);
    k_down<<<1024,256,0,stream>>>(Wd, act, xres, out);
}